// Round 5
// baseline (303.731 us; speedup 1.0000x reference)
//
#include <hip/hip_runtime.h>
#include <math.h>

typedef unsigned short u16;
typedef unsigned int u32;
typedef __fp16 fp16x2 __attribute__((ext_vector_type(2)));
typedef _Float16 half8 __attribute__((ext_vector_type(8)));
typedef float f32x4 __attribute__((ext_vector_type(4)));

#define NH   12
#define SEQ  2048
#define CDIM 768

__device__ __forceinline__ u16 f2h(float f) {
  _Float16 h = (_Float16)f;                       // v_cvt_f16_f32 (RNE)
  return __builtin_bit_cast(u16, h);
}
__device__ __forceinline__ u32 pk2(float a, float b) {
  fp16x2 h = __builtin_amdgcn_cvt_pkrtz(a, b);    // single v_cvt_pk_rtz_f16_f32
  return __builtin_bit_cast(u32, h);
}
__device__ __forceinline__ uint4 cvt8(float4 f0, float4 f1) {
  return make_uint4(pk2(f0.x, f0.y), pk2(f0.z, f0.w), pk2(f1.x, f1.y), pk2(f1.z, f1.w));
}

// ---------------- NT GEMM: C[M,N] = A[M,K] @ B[N,K]^T, f16 MFMA, fp32 acc ---
// Tile 128(M) x 64(N), 4 waves 2x2, wave tile 64x32. B always fp32 (weights),
// converted in-register during staging. A fp32 for MODE 0/1, f16 for MODE 2.
// MODE 0: out0 = q [B,H,N,D] f16, scaled by qkscale(tau)*log2e
// MODE 1: cols [0,768)->k [B,H,N,D]; [768,1536)->v transposed [B,H,D,N]
// MODE 2: fp32 out[M,N] = acc + bias[n]
template<int MODE>
__global__ __launch_bounds__(256, 4) void gemm_nt(
    const void* __restrict__ Av, const float* __restrict__ Bf,
    u16* __restrict__ out0, u16* __restrict__ out1,
    float* __restrict__ outf, const float* __restrict__ bias,
    const float* __restrict__ taup, int M, int N, int K)
{
  constexpr bool AF32 = (MODE != 2);
  constexpr int LD = 40;                       // 80 B row stride: 16B-aligned, 2-way-max banks
  __shared__ __align__(16) u16 As[128 * LD];
  __shared__ __align__(16) u16 Bs[64 * LD];
  const int tid = threadIdx.x;
  const int wave = tid >> 6, lane = tid & 63;
  const int quad = lane >> 4, l16 = lane & 15;
  const int row0 = blockIdx.x * 128, col0 = blockIdx.y * 64;
  const int wm = (wave >> 1) * 64, wn = (wave & 1) * 32;

  const int ra = tid >> 2, ca = (tid & 3) * 8;  // 8-elem chunks; A rows ra, ra+64; B row ra
  const float* Af = (const float*)Av;
  const u16*   Ah = (const u16*)Av;

  f32x4 acc[4][2] = {};

  float4 pa0a, pa0b, pa1a, pa1b;
  uint4  ha0, ha1;
  if constexpr (AF32) {
    pa0a = *(const float4*)(Af + (size_t)(row0 + ra) * K + ca);
    pa0b = *(const float4*)(Af + (size_t)(row0 + ra) * K + ca + 4);
    pa1a = *(const float4*)(Af + (size_t)(row0 + ra + 64) * K + ca);
    pa1b = *(const float4*)(Af + (size_t)(row0 + ra + 64) * K + ca + 4);
  } else {
    ha0 = *(const uint4*)(Ah + (size_t)(row0 + ra) * K + ca);
    ha1 = *(const uint4*)(Ah + (size_t)(row0 + ra + 64) * K + ca);
  }
  float4 pb0 = *(const float4*)(Bf + (size_t)(col0 + ra) * K + ca);
  float4 pb1 = *(const float4*)(Bf + (size_t)(col0 + ra) * K + ca + 4);

  for (int k0 = 0; k0 < K; k0 += 32) {
    __syncthreads();
    if constexpr (AF32) {
      *(uint4*)(&As[ra * LD + ca])        = cvt8(pa0a, pa0b);
      *(uint4*)(&As[(ra + 64) * LD + ca]) = cvt8(pa1a, pa1b);
    } else {
      *(uint4*)(&As[ra * LD + ca])        = ha0;
      *(uint4*)(&As[(ra + 64) * LD + ca]) = ha1;
    }
    *(uint4*)(&Bs[ra * LD + ca]) = cvt8(pb0, pb1);
    if (k0 + 32 < K) {
      int kn = k0 + 32 + ca;
      if constexpr (AF32) {
        pa0a = *(const float4*)(Af + (size_t)(row0 + ra) * K + kn);
        pa0b = *(const float4*)(Af + (size_t)(row0 + ra) * K + kn + 4);
        pa1a = *(const float4*)(Af + (size_t)(row0 + ra + 64) * K + kn);
        pa1b = *(const float4*)(Af + (size_t)(row0 + ra + 64) * K + kn + 4);
      } else {
        ha0 = *(const uint4*)(Ah + (size_t)(row0 + ra) * K + kn);
        ha1 = *(const uint4*)(Ah + (size_t)(row0 + ra + 64) * K + kn);
      }
      pb0 = *(const float4*)(Bf + (size_t)(col0 + ra) * K + kn);
      pb1 = *(const float4*)(Bf + (size_t)(col0 + ra) * K + kn + 4);
    }
    __syncthreads();
    half8 af[4], bfr[2];
    #pragma unroll
    for (int mt = 0; mt < 4; mt++)
      af[mt] = *(const half8*)&As[(wm + mt * 16 + l16) * LD + quad * 8];
    #pragma unroll
    for (int nt = 0; nt < 2; nt++)
      bfr[nt] = *(const half8*)&Bs[(wn + nt * 16 + l16) * LD + quad * 8];
    #pragma unroll
    for (int mt = 0; mt < 4; mt++)
      #pragma unroll
      for (int nt = 0; nt < 2; nt++)
        acc[mt][nt] = __builtin_amdgcn_mfma_f32_16x16x32_f16(af[mt], bfr[nt], acc[mt][nt], 0, 0, 0);
  }

  float qkscale = 1.f;
  if (MODE == 0) {
    float t = *taup;
    float sp = (t > 20.f) ? t : log1pf(expf(t));
    qkscale = (0.125f / (sp + 1e-6f)) * 1.44269504088896340736f;  // fold log2(e)
  }

  // epilogue: C layout col=lane&15, row=quad*4+reg
  #pragma unroll
  for (int mt = 0; mt < 4; mt++)
  #pragma unroll
  for (int nt = 0; nt < 2; nt++)
  #pragma unroll
  for (int r = 0; r < 4; r++) {
    int gm = row0 + wm + mt * 16 + quad * 4 + r;
    int gn = col0 + wn + nt * 16 + l16;
    float v = acc[mt][nt][r];
    if (MODE == 0) {
      int b = gm >> 11, n = gm & 2047;
      int h = gn >> 6, d = gn & 63;
      out0[(((size_t)(b * NH + h)) * SEQ + n) * 64 + d] = f2h(v * qkscale);
    } else if (MODE == 1) {
      int b = gm >> 11, n = gm & 2047;
      if (gn < CDIM) {
        int h = gn >> 6, d = gn & 63;
        out0[(((size_t)(b * NH + h)) * SEQ + n) * 64 + d] = f2h(v);
      } else {
        int c = gn - CDIM;
        int h = c >> 6, d = c & 63;
        out1[(((size_t)(b * NH + h)) * 64 + d) * SEQ + n] = f2h(v);   // V^T: [B,H,D,N]
      }
    } else {
      outf[(size_t)gm * N + gn] = v + bias[gn];
    }
  }
}

// ---------------- flash attention (transposed-S, f16) ----------------
// grid 48*(16 q-tiles of 128). 4 waves, 32 q-rows/wave. KV tile 64.
// St = K Q^T so softmax rows live per-lane; P packed via cvt_pkrtz.
__global__ __launch_bounds__(256, 3) void attn_kernel(
    const u16* __restrict__ Q, const u16* __restrict__ Kb,
    const u16* __restrict__ Vtg, u16* __restrict__ Ob)
{
  constexpr int LDK = 72;                      // 144 B rows: 16B-aligned
  __shared__ __align__(16) u16 Ks[64 * LDK];   // [kk][d]
  __shared__ __align__(16) u16 Vs[64 * LDK];   // [d][kk]
  __shared__ __align__(16) u16 Ps[4 * 16 * LDK];

  const int qt = blockIdx.x & 15;
  const int bh = blockIdx.x >> 4;
  const int b = bh / NH, h = bh % NH;
  const u16* Qp = Q   + (size_t)bh * SEQ * 64;
  const u16* Kp = Kb  + (size_t)bh * SEQ * 64;
  const u16* Vp = Vtg + (size_t)bh * 64 * SEQ;

  const int tid = threadIdx.x;
  const int wave = tid >> 6, lane = tid & 63;
  const int quad = lane >> 4, l16 = lane & 15;
  u16* Pw = Ps + wave * 16 * LDK;

  // Q fragments (B-operand): Q[m=l16][d=ks*32+quad*8+j], pre-scaled
  half8 qf[2][2];
  #pragma unroll
  for (int mt = 0; mt < 2; mt++)
    #pragma unroll
    for (int ks = 0; ks < 2; ks++)
      qf[mt][ks] = *(const half8*)(Qp + (size_t)(qt * 128 + wave * 32 + mt * 16 + l16) * 64 + ks * 32 + quad * 8);

  const int r0 = tid >> 3, c0 = (tid & 7) * 8;
  const int r1 = r0 + 32;
  uint4 kpre0 = *(const uint4*)(Kp + (size_t)r0 * 64 + c0);
  uint4 kpre1 = *(const uint4*)(Kp + (size_t)r1 * 64 + c0);
  uint4 vpre0 = *(const uint4*)(Vp + (size_t)r0 * SEQ + c0);
  uint4 vpre1 = *(const uint4*)(Vp + (size_t)r1 * SEQ + c0);

  f32x4 oacc[2][4] = {};
  float mrow[2] = {-1e30f, -1e30f}, lrow[2] = {0.f, 0.f};

  for (int kt = 0; kt < SEQ / 64; kt++) {
    __syncthreads();
    *(uint4*)(&Ks[r0 * LDK + c0]) = kpre0;
    *(uint4*)(&Ks[r1 * LDK + c0]) = kpre1;
    *(uint4*)(&Vs[r0 * LDK + c0]) = vpre0;
    *(uint4*)(&Vs[r1 * LDK + c0]) = vpre1;
    if (kt + 1 < SEQ / 64) {
      int nb = (kt + 1) * 64;
      kpre0 = *(const uint4*)(Kp + (size_t)(nb + r0) * 64 + c0);
      kpre1 = *(const uint4*)(Kp + (size_t)(nb + r1) * 64 + c0);
      vpre0 = *(const uint4*)(Vp + (size_t)r0 * SEQ + nb + c0);
      vpre1 = *(const uint4*)(Vp + (size_t)r1 * SEQ + nb + c0);
    }
    __syncthreads();

    // St = K Q^T : sacc[mt][ntk] holds St[kk=ntk*16+quad*4+r][m=l16]
    f32x4 sacc[2][4] = {};
    #pragma unroll
    for (int ks = 0; ks < 2; ks++) {
      #pragma unroll
      for (int ntk = 0; ntk < 4; ntk++) {
        half8 kf = *(const half8*)&Ks[(ntk * 16 + l16) * LDK + ks * 32 + quad * 8];
        #pragma unroll
        for (int mt = 0; mt < 2; mt++)
          sacc[mt][ntk] = __builtin_amdgcn_mfma_f32_16x16x32_f16(kf, qf[mt][ks], sacc[mt][ntk], 0, 0, 0);
      }
    }

    half8 pf[2][2];
    #pragma unroll
    for (int mt = 0; mt < 2; mt++) {
      float tmax = -1e30f;
      #pragma unroll
      for (int ntk = 0; ntk < 4; ntk++)
        #pragma unroll
        for (int r = 0; r < 4; r++)
          tmax = fmaxf(tmax, sacc[mt][ntk][r]);
      tmax = fmaxf(tmax, __shfl_xor(tmax, 16));
      tmax = fmaxf(tmax, __shfl_xor(tmax, 32));
      float mold = mrow[mt];
      float mnew = fmaxf(mold, tmax);
      float alpha = exp2f(mold - mnew);
      mrow[mt] = mnew;

      float rs = 0.f;
      #pragma unroll
      for (int ntk = 0; ntk < 4; ntk++) {
        float p0 = exp2f(sacc[mt][ntk][0] - mnew);
        float p1 = exp2f(sacc[mt][ntk][1] - mnew);
        float p2 = exp2f(sacc[mt][ntk][2] - mnew);
        float p3 = exp2f(sacc[mt][ntk][3] - mnew);
        rs += (p0 + p1) + (p2 + p3);
        *(uint2*)(&Pw[l16 * LDK + ntk * 16 + quad * 4]) = make_uint2(pk2(p0, p1), pk2(p2, p3));
      }
      rs += __shfl_xor(rs, 16);
      rs += __shfl_xor(rs, 32);
      lrow[mt] = lrow[mt] * alpha + rs;

      // O rescale only when some row's max actually advanced (alpha<1)
      if (__any(mnew > mold)) {
        float av[4];
        #pragma unroll
        for (int r = 0; r < 4; r++) av[r] = __shfl(alpha, quad * 4 + r);
        #pragma unroll
        for (int dt = 0; dt < 4; dt++)
          #pragma unroll
          for (int r = 0; r < 4; r++)
            oacc[mt][dt][r] *= av[r];
      }

      pf[mt][0] = *(const half8*)&Pw[l16 * LDK + quad * 8];
      pf[mt][1] = *(const half8*)&Pw[l16 * LDK + 32 + quad * 8];
    }

    // O += P V
    #pragma unroll
    for (int ks = 0; ks < 2; ks++)
      #pragma unroll
      for (int dt = 0; dt < 4; dt++) {
        half8 vf = *(const half8*)&Vs[(dt * 16 + l16) * LDK + ks * 32 + quad * 8];
        #pragma unroll
        for (int mt = 0; mt < 2; mt++)
          oacc[mt][dt] = __builtin_amdgcn_mfma_f32_16x16x32_f16(pf[mt][ks], vf, oacc[mt][dt], 0, 0, 0);
      }
  }

  // epilogue: O / l -> ao[b][n][h*64+d] (f16)
  #pragma unroll
  for (int mt = 0; mt < 2; mt++) {
    float lv[4];
    #pragma unroll
    for (int r = 0; r < 4; r++) lv[r] = __shfl(lrow[mt], quad * 4 + r);
    #pragma unroll
    for (int r = 0; r < 4; r++) {
      float inv = 1.0f / lv[r];
      int n = qt * 128 + wave * 32 + mt * 16 + quad * 4 + r;
      size_t base = ((size_t)b * SEQ + n) * CDIM + h * 64;
      #pragma unroll
      for (int dt = 0; dt < 4; dt++)
        Ob[base + dt * 16 + l16] = f2h(oacc[mt][dt][r] * inv);
    }
  }
}

// ---------------- launch ----------------
extern "C" void kernel_launch(void* const* d_in, const int* in_sizes, int n_in,
                              void* d_out, int out_size, void* d_ws, size_t ws_size,
                              hipStream_t stream)
{
  const float* x     = (const float*)d_in[0];
  const float* y     = (const float*)d_in[1];
  const float* Wq    = (const float*)d_in[2];
  const float* Wkv   = (const float*)d_in[3];
  const float* taup  = (const float*)d_in[4];
  const float* Wproj = (const float*)d_in[5];
  const float* bproj = (const float*)d_in[6];
  float* out = (float*)d_out;

  char* ws = (char*)d_ws;
  size_t off = 0;
  auto alloc = [&](size_t bytes) { char* p = ws + off; off += bytes; return p; };
  u16* qb  = (u16*)alloc(8192ull * 768 * 2);   // [B,H,N,D] f16, pre-scaled
  u16* kb  = (u16*)alloc(8192ull * 768 * 2);   // [B,H,N,D]
  u16* vtb = (u16*)alloc(8192ull * 768 * 2);   // [B,H,D,N]
  u16* ao  = (u16*)alloc(8192ull * 768 * 2);   // [B,N,C]

  gemm_nt<0><<<dim3(64, 12), 256, 0, stream>>>((const void*)x, Wq, qb, nullptr, nullptr, nullptr, taup, 8192, 768, 768);
  gemm_nt<1><<<dim3(64, 24), 256, 0, stream>>>((const void*)y, Wkv, kb, vtb, nullptr, nullptr, nullptr, 8192, 1536, 768);
  attn_kernel<<<dim3(48 * 16), 256, 0, stream>>>(qb, kb, vtb, ao);
  gemm_nt<2><<<dim3(64, 12), 256, 0, stream>>>((const void*)ao, Wproj, nullptr, nullptr, out, bproj, nullptr, 8192, 768, 768);
}